// Round 15
// baseline (94.520 us; speedup 1.0000x reference)
//
#include <hip/hip_runtime.h>
#include <hip/hip_bf16.h>

#define GRID_D 128
#define NSITES (GRID_D * GRID_D)   // 16384
#define HID 64
#define BATCH 64

#define WPB 4                       // waves per block
#define BLOCKS 1024                 // full single-shot residency: 4096 waves
#define BLOCKS_PER_BATCH (BLOCKS / BATCH)        // 16
#define WAVES_PER_BATCH (BLOCKS_PER_BATCH * WPB) // 64
#define SITES_PER_WAVE (NSITES / WAVES_PER_BATCH) // 256
#define ITERS (SITES_PER_WAVE / 64)               // 4

typedef short bf16x8 __attribute__((ext_vector_type(8)));
typedef float f32x4  __attribute__((ext_vector_type(4)));

__device__ __forceinline__ unsigned short f2bf(float f) {
    return __builtin_bit_cast(unsigned short, __float2bfloat16(f));
}

// packed RNE f32->bf16 pair: dst = {lo16: bf16(a), hi16: bf16(b)}
__device__ __forceinline__ unsigned cvt_pk_bf16(float a, float b) {
    unsigned r;
    asm("v_cvt_pk_bf16_f32 %0, %1, %2" : "=v"(r) : "v"(a), "v"(b));
    return r;
}

union frag_u { bf16x8 v; unsigned u[4]; unsigned short us[8]; };

// Both layers on MFMA (k-map verified R11); 64 distinct sites/iter (R13).
// R15: (1) reduction folded into this kernel via atomicAdd (512 atomics on 64
// addrs -- removes gauge_reduce dispatch + gap); (2) 2-deep s-phase pipeline:
// iter t+1's gather+dots+cvt_pk computed BEFORE iter t's group processing so
// the dependent load chain hides under MFMA/pack work (R8 only pipelined raw
// loads, which the compiler had already hoisted -- this moves the whole
// s-computation across the MFMA phase).
// kappa(kg,i) = s*32 + ((i&4)<<2) + kg*4 + (i&3), baked into bfrag gather;
// emb-MFMA D layout: col=lane&15=site-in-group, row=(lane>>4)*4+r=khid_local.
// R4: no min-waves bound (spill). R13/R14: inner VALU count is NOT the
// bottleneck (three nulls); gauge ~36us vs ~8us issue-bound.
__global__ __launch_bounds__(256)
void gauge_mfma(const float* __restrict__ x,
                const float* __restrict__ H,
                const float* __restrict__ W_emb,
                const float* __restrict__ b_emb,
                const float* __restrict__ W_hid,
                const float* __restrict__ b_hid,
                const float* __restrict__ W_post,
                const float* __restrict__ b_post,
                float* __restrict__ out)
{
    const int tid   = threadIdx.x;
    const int lane  = tid & 63;
    const int widx  = tid >> 6;
    const int wgid  = blockIdx.x * WPB + widx;
    const int b     = wgid / WAVES_PER_BATCH;
    const int wslot = wgid % WAVES_PER_BATCH;

    const int  ls  = lane & 15;    // col within 16-wide fragment
    const int  kg  = lane >> 4;    // k-group
    const bool kg0 = (kg == 0);

    const float h00 = H[0], h01 = H[1], h10 = H[2], h11 = H[3];

    // ---- hidden-layer B fragments, kappa k-map, packed conversion
    bf16x8 bfrag[4][2];
    #pragma unroll
    for (int t = 0; t < 4; ++t) {
        #pragma unroll
        for (int s = 0; s < 2; ++s) {
            frag_u r;
            #pragma unroll
            for (int j = 0; j < 4; ++j) {
                const int i    = 2 * j;
                const int khid = s * 32 + ((i & 4) << 2) + (kg << 2) + (i & 3);
                r.u[j] = cvt_pk_bf16(W_hid[khid * HID + t * 16 + ls],
                                     W_hid[(khid + 1) * HID + t * 16 + ls]);
            }
            bfrag[t][s] = r.v;
        }
    }

    // ---- embedding A fragments: row ls <-> khid = m*16+ls; k-slots (kg0):
    // kemb 0..3 = W_emb rows, slot 4 = b_emb (bias rides B-slot of 1.0)
    bf16x8 afe[4];
    #pragma unroll
    for (int m = 0; m < 4; ++m) {
        const int col = m * 16 + ls;
        frag_u r;
        r.u[0] = kg0 ? cvt_pk_bf16(W_emb[0 * HID + col], W_emb[1 * HID + col]) : 0u;
        r.u[1] = kg0 ? cvt_pk_bf16(W_emb[2 * HID + col], W_emb[3 * HID + col]) : 0u;
        r.u[2] = kg0 ? (unsigned)f2bf(b_emb[col]) : 0u;
        r.u[3] = 0u;
        afe[m] = r.v;
    }

    // per-lane bias / post-weight per N-tile (col = t*16+ls)
    float bh[4], wp[4];
    #pragma unroll
    for (int t = 0; t < 4; ++t) {
        bh[t] = b_hid[t * 16 + ls];
        wp[t] = W_post[t * 16 + ls];
    }

    const float* __restrict__ xb = x + (size_t)b * NSITES * 2;
    const int wbase = wslot * SITES_PER_WAVE;
    const unsigned sd2 = kg0 ? 0x00003F80u : 0u;   // B slot4 = bf16(1.0)
    float o0 = 0.f, o1 = 0.f, o2 = 0.f, o3 = 0.f;

    // s-phase for one iteration: gather 5 float2 + 4 gauge dots + 2 cvt_pk
    auto s_phase = [&](int it, unsigned& p01, unsigned& p23) {
        const int site = wbase + it * 64 + lane;
        const int xc = site & (GRID_D - 1);
        const int yc = site >> 7;
        const int n0 = xc + (((yc + 1) & (GRID_D - 1)) << 7);
        const int n1 = xc + (((yc - 1) & (GRID_D - 1)) << 7);
        const int n2 = ((xc - 1) & (GRID_D - 1)) + (yc << 7);
        const int n3 = ((xc + 1) & (GRID_D - 1)) + (yc << 7);
        const float2 xi = *(const float2*)(xb + 2 * site);
        const float2 xu = *(const float2*)(xb + 2 * n0);
        const float2 xd = *(const float2*)(xb + 2 * n1);
        const float2 xl = *(const float2*)(xb + 2 * n2);
        const float2 xr = *(const float2*)(xb + 2 * n3);
        const float s0 = xi.x * fmaf(h00, xu.x, h01 * xu.y) + xi.y * fmaf(h10, xu.x, h11 * xu.y);
        const float s1 = xi.x * fmaf(h00, xd.x, h01 * xd.y) + xi.y * fmaf(h10, xd.x, h11 * xd.y);
        const float s2 = xi.x * fmaf(h00, xl.x, h01 * xl.y) + xi.y * fmaf(h10, xl.x, h11 * xl.y);
        const float s3 = xi.x * fmaf(h00, xr.x, h01 * xr.y) + xi.y * fmaf(h10, xr.x, h11 * xr.y);
        p01 = cvt_pk_bf16(s0, s1);
        p23 = cvt_pk_bf16(s2, s3);
    };

    unsigned p01c, p23c, p01n, p23n;
    s_phase(0, p01c, p23c);            // prologue

    for (int it = 0; it < ITERS; ++it) {
        if (it + 1 < ITERS)
            s_phase(it + 1, p01n, p23n);   // overlap next s-phase with groups

        // ---- 4 site-groups of 16; shuffle s-packs to kg0 lanes' k-slots
        #pragma unroll
        for (int g = 0; g < 4; ++g) {
            const unsigned q0 = __shfl(p01c, (g << 4) + ls, 64);
            const unsigned q1 = __shfl(p23c, (g << 4) + ls, 64);
            frag_u bs;
            bs.u[0] = kg0 ? q0 : 0u;
            bs.u[1] = kg0 ? q1 : 0u;
            bs.u[2] = sd2;
            bs.u[3] = 0u;

            // embedding: 4 MFMAs -> h1 (bias included, pre-relu)
            f32x4 D0 = {0.f, 0.f, 0.f, 0.f};
            f32x4 D1 = {0.f, 0.f, 0.f, 0.f};
            f32x4 D2 = {0.f, 0.f, 0.f, 0.f};
            f32x4 D3 = {0.f, 0.f, 0.f, 0.f};
            D0 = __builtin_amdgcn_mfma_f32_16x16x32_bf16(afe[0], bs.v, D0, 0, 0, 0);
            D1 = __builtin_amdgcn_mfma_f32_16x16x32_bf16(afe[1], bs.v, D1, 0, 0, 0);
            D2 = __builtin_amdgcn_mfma_f32_16x16x32_bf16(afe[2], bs.v, D2, 0, 0, 0);
            D3 = __builtin_amdgcn_mfma_f32_16x16x32_bf16(afe[3], bs.v, D3, 0, 0, 0);

            #pragma unroll
            for (int r = 0; r < 4; ++r) {
                D0[r] = fmaxf(D0[r], 0.0f);
                D1[r] = fmaxf(D1[r], 0.0f);
                D2[r] = fmaxf(D2[r], 0.0f);
                D3[r] = fmaxf(D3[r], 0.0f);
            }
            frag_u ah0, ah1;
            ah0.u[0] = cvt_pk_bf16(D0[0], D0[1]);
            ah0.u[1] = cvt_pk_bf16(D0[2], D0[3]);
            ah0.u[2] = cvt_pk_bf16(D1[0], D1[1]);
            ah0.u[3] = cvt_pk_bf16(D1[2], D1[3]);
            ah1.u[0] = cvt_pk_bf16(D2[0], D2[1]);
            ah1.u[1] = cvt_pk_bf16(D2[2], D2[3]);
            ah1.u[2] = cvt_pk_bf16(D3[0], D3[1]);
            ah1.u[3] = cvt_pk_bf16(D3[2], D3[3]);

            // hidden layer: 8 MFMAs + fused relu/post epilogue
            {
                f32x4 acc = { bh[0], bh[0], bh[0], bh[0] };
                acc = __builtin_amdgcn_mfma_f32_16x16x32_bf16(ah0.v, bfrag[0][0], acc, 0, 0, 0);
                acc = __builtin_amdgcn_mfma_f32_16x16x32_bf16(ah1.v, bfrag[0][1], acc, 0, 0, 0);
                #pragma unroll
                for (int r = 0; r < 4; ++r) o0 = fmaf(fmaxf(acc[r], 0.0f), wp[0], o0);
            }
            {
                f32x4 acc = { bh[1], bh[1], bh[1], bh[1] };
                acc = __builtin_amdgcn_mfma_f32_16x16x32_bf16(ah0.v, bfrag[1][0], acc, 0, 0, 0);
                acc = __builtin_amdgcn_mfma_f32_16x16x32_bf16(ah1.v, bfrag[1][1], acc, 0, 0, 0);
                #pragma unroll
                for (int r = 0; r < 4; ++r) o1 = fmaf(fmaxf(acc[r], 0.0f), wp[1], o1);
            }
            {
                f32x4 acc = { bh[2], bh[2], bh[2], bh[2] };
                acc = __builtin_amdgcn_mfma_f32_16x16x32_bf16(ah0.v, bfrag[2][0], acc, 0, 0, 0);
                acc = __builtin_amdgcn_mfma_f32_16x16x32_bf16(ah1.v, bfrag[2][1], acc, 0, 0, 0);
                #pragma unroll
                for (int r = 0; r < 4; ++r) o2 = fmaf(fmaxf(acc[r], 0.0f), wp[2], o2);
            }
            {
                f32x4 acc = { bh[3], bh[3], bh[3], bh[3] };
                acc = __builtin_amdgcn_mfma_f32_16x16x32_bf16(ah0.v, bfrag[3][0], acc, 0, 0, 0);
                acc = __builtin_amdgcn_mfma_f32_16x16x32_bf16(ah1.v, bfrag[3][1], acc, 0, 0, 0);
                #pragma unroll
                for (int r = 0; r < 4; ++r) o3 = fmaf(fmaxf(acc[r], 0.0f), wp[3], o3);
            }
        }
        p01c = p01n; p23c = p23n;
    }

    float o = (o0 + o1) + (o2 + o3);

    // wave reduce, block reduce, ONE atomic per block (bias added once/batch)
    #pragma unroll
    for (int off = 32; off > 0; off >>= 1)
        o += __shfl_down(o, off, 64);

    __shared__ float part[WPB];
    if (lane == 0) part[widx] = o;
    __syncthreads();
    if (tid == 0) {
        float t = part[0] + part[1] + part[2] + part[3];
        if ((blockIdx.x % BLOCKS_PER_BATCH) == 0)
            t += (float)NSITES * b_post[0];
        atomicAdd(&out[b], t);
    }
}

extern "C" void kernel_launch(void* const* d_in, const int* in_sizes, int n_in,
                              void* d_out, int out_size, void* d_ws, size_t ws_size,
                              hipStream_t stream)
{
    const float* x      = (const float*)d_in[0];
    const float* H      = (const float*)d_in[1];
    const float* W_emb  = (const float*)d_in[2];
    const float* b_emb  = (const float*)d_in[3];
    const float* W_hid  = (const float*)d_in[4];
    const float* b_hid  = (const float*)d_in[5];
    const float* W_post = (const float*)d_in[6];
    const float* b_post = (const float*)d_in[7];
    float* out = (float*)d_out;

    // out is poisoned 0xAA before every timed launch; atomics need zeros
    hipMemsetAsync(out, 0, (size_t)out_size * sizeof(float), stream);

    gauge_mfma<<<dim3(BLOCKS), dim3(256), 0, stream>>>(
        x, H, W_emb, b_emb, W_hid, b_hid, W_post, b_post, out);
}